// Round 1
// baseline (238.637 us; speedup 1.0000x reference)
//
#include <hip/hip_runtime.h>

// out[n, t] = sum_{j <= t} W[t, j] * x[n, j] + b[t]
// B = 1048576, T = 32, fp32 in/out. Memory-bound (~268 MB @ ~6.3 TB/s -> ~43 us).

constexpr int T    = 32;
constexpr int ROWS = 256;         // rows per block (== block size: 1 thread per row)
constexpr int RSTR = T + 1;       // padded LDS row stride (33) -> conflict-free row reads

__global__ __launch_bounds__(256) void triu_kernel(
    const float* __restrict__ x, const float* __restrict__ W,
    const float* __restrict__ b, float* __restrict__ out)
{
    __shared__ float sW[T * T];
    __shared__ float sb[T];
    __shared__ float sX[ROWS * RSTR];

    const int tid = threadIdx.x;

    // Stage W and b once per block (reads later are wave-uniform -> LDS broadcast).
    #pragma unroll
    for (int i = tid; i < T * T; i += 256) sW[i] = W[i];
    if (tid < T) sb[tid] = b[tid];

    const long long base = (long long)blockIdx.x * (ROWS * T);

    // Coalesced float4 staging of the 256x32 input tile into padded LDS.
    const float4* __restrict__ x4 = reinterpret_cast<const float4*>(x + base);
    #pragma unroll
    for (int it = 0; it < (ROWS * T) / (256 * 4); ++it) {   // 8 iters
        const int idx = it * 256 + tid;      // float4 index in tile
        const float4 v = x4[idx];
        const int row = idx >> 3;            // (idx*4)/32
        const int col = (idx & 7) << 2;      // (idx*4)%32
        const int p = row * RSTR + col;
        sX[p + 0] = v.x; sX[p + 1] = v.y; sX[p + 2] = v.z; sX[p + 3] = v.w;
    }
    __syncthreads();

    // Each thread: one row. Triangular FMA, j is uniform -> no divergence.
    float acc[T];
    #pragma unroll
    for (int t = 0; t < T; ++t) acc[t] = sb[t];

    float* myrow = &sX[tid * RSTR];
    #pragma unroll
    for (int j = 0; j < T; ++j) {
        const float xj = myrow[j];           // bank = (lane + j) % 32 -> conflict-free
        #pragma unroll
        for (int t = j; t < T; ++t)
            acc[t] = fmaf(sW[t * T + j], xj, acc[t]);   // sW: wave-uniform broadcast
    }

    // Overwrite own row in LDS with the result (no cross-thread hazard).
    #pragma unroll
    for (int t = 0; t < T; ++t) myrow[t] = acc[t];
    __syncthreads();

    // Coalesced float4 stores.
    float4* __restrict__ o4 = reinterpret_cast<float4*>(out + base);
    #pragma unroll
    for (int it = 0; it < 8; ++it) {
        const int idx = it * 256 + tid;
        const int row = idx >> 3;
        const int col = (idx & 7) << 2;
        const int p = row * RSTR + col;
        o4[idx] = make_float4(sX[p + 0], sX[p + 1], sX[p + 2], sX[p + 3]);
    }
}

extern "C" void kernel_launch(void* const* d_in, const int* in_sizes, int n_in,
                              void* d_out, int out_size, void* d_ws, size_t ws_size,
                              hipStream_t stream) {
    const float* x  = (const float*)d_in[0];   // [B, 32]
    const float* W  = (const float*)d_in[1];   // [32, 32] (lower-tri used)
    const float* b  = (const float*)d_in[2];   // [32]
    float* out      = (float*)d_out;           // [B, 32]

    const int batch = in_sizes[0] / T;         // 1048576
    const int grid  = batch / ROWS;            // 4096 blocks
    triu_kernel<<<grid, 256, 0, stream>>>(x, W, b, out);
}